// Round 5
// baseline (183.735 us; speedup 1.0000x reference)
//
#include <hip/hip_runtime.h>

#define N_FFT 4096
#define NH    2048          // N_FFT/2 (complex FFT length)
#define NBINS 2049          // N_FFT/2 + 1
#define NLAGS 81            // 2*MAX_TAU + 1
#define MAXTAU 40
#define NSEG  8             // k-segments per (b,p) pair
#define SEGLEN 256
#define PI_D 3.14159265358979323846

// ---------------------------------------------------------------------------
// Kernel 0: twiddle tables + zero the argmax tickets (runs first every call).
// ---------------------------------------------------------------------------
__global__ void table_kernel(double2* __restrict__ tw_fft,
                             double2* __restrict__ tw_post,
                             int* __restrict__ ticket, int B) {
    int idx = blockIdx.x * 256 + (int)threadIdx.x;
    if (idx < 1024) {
        double sv, cv;
        sincos(-(2.0 * PI_D / (double)NH) * (double)idx, &sv, &cv);
        tw_fft[idx] = make_double2(cv, sv);
    } else if (idx < 1024 + NBINS) {
        int k = idx - 1024;
        double sv, cv;
        sincos(-(2.0 * PI_D / (double)N_FFT) * (double)k, &sv, &cv);
        tw_post[k] = make_double2(cv, sv);
    }
    if (idx < B) ticket[idx] = 0;
}

// ---------------------------------------------------------------------------
// Kernel 1: rfft per (b,m) channel, fp64, packed-complex radix-2 FFT in LDS.
// ---------------------------------------------------------------------------
__global__ __launch_bounds__(1024)
void rfft_kernel(const float* __restrict__ sig,
                 const double2* __restrict__ tw_fft,
                 const double2* __restrict__ tw_post,
                 double* __restrict__ S) {
    int bm  = blockIdx.x;
    int tid = (int)threadIdx.x;

    __shared__ double2 data[NH];   // 32 KB

    const float2* sp = (const float2*)(sig + (size_t)bm * N_FFT);
    for (int i = tid; i < NH; i += 1024) {
        float2 v = sp[i];
        int j = (int)(__brev((unsigned)i) >> 21);   // 11-bit reverse
        data[j] = make_double2((double)v.x, (double)v.y);
    }
    __syncthreads();

    for (int s = 1; s <= 11; ++s) {
        int half = 1 << (s - 1);
        int t  = tid;
        int g  = t >> (s - 1);
        int j  = t & (half - 1);
        int i0 = (g << s) + j;
        int i1 = i0 + half;
        double2 w = tw_fft[j << (11 - s)];
        double2 u = data[i0];
        double2 v = data[i1];
        double vr = v.x * w.x - v.y * w.y;
        double vi = v.x * w.y + v.y * w.x;
        data[i0] = make_double2(u.x + vr, u.y + vi);
        data[i1] = make_double2(u.x - vr, u.y - vi);
        __syncthreads();
    }

    double* So = S + (size_t)bm * NBINS * 2;
    for (int k = tid; k < NBINS; k += 1024) {
        double2 Zk = data[k & (NH - 1)];
        double2 Zm = data[(NH - k) & (NH - 1)];
        double er = 0.5 * (Zk.x + Zm.x);
        double ei = 0.5 * (Zk.y - Zm.y);
        double dr = Zk.x - Zm.x;
        double di = Zk.y + Zm.y;
        double orr = 0.5 * di;       // O = -i*d/2
        double oii = -0.5 * dr;
        double2 w = tw_post[k];
        So[k * 2]     = er + w.x * orr - w.y * oii;
        So[k * 2 + 1] = ei + w.x * oii + w.y * orr;
    }
}

// ---------------------------------------------------------------------------
// Kernel 2: per (b,p,seg): PHAT (irfft weight folded) for 256(+1) bins into
// LDS, then lag partials via n/-n symmetry:
//   Cr(n) = sum_k w*phr*cos(2pi k n/N), Ci(n) = sum_k w*phi*sin(2pi k n/N)
//   part[40+n] = Cr-Ci ; part[40-n] = Cr+Ci
// Phase 2: 41 |n| values x 6 chunks of 43 bins = 246 threads.
// ---------------------------------------------------------------------------
#define NCH 6
#define CHLEN 43
__global__ __launch_bounds__(256)
void phat_cc_part_kernel(const double* __restrict__ S,
                         const int* __restrict__ comb,
                         double* __restrict__ cc_part, int P) {
    int id  = (int)blockIdx.x;
    int seg = id & (NSEG - 1);
    int bp  = id >> 3;
    int b   = bp / P;
    int p   = bp % P;
    int ma = comb[p * 2 + 0];
    int mb = comb[p * 2 + 1];
    const double2* Sa = (const double2*)(S + ((size_t)(b * 8 + ma)) * NBINS * 2);
    const double2* Sb = (const double2*)(S + ((size_t)(b * 8 + mb)) * NBINS * 2);

    int k0 = seg * SEGLEN;
    int k1 = (seg == NSEG - 1) ? NBINS : (k0 + SEGLEN);   // last seg: 257 bins

    __shared__ double2 phs[SEGLEN + 1];       // 4,112 B
    __shared__ double partCr[41 * NCH];       // 1,968 B
    __shared__ double partCi[41 * NCH];

    int tid = (int)threadIdx.x;
    for (int k = k0 + tid; k < k1; k += 256) {
        double2 a = Sa[k];
        double2 c = Sb[k];
        double Xr = a.x * c.x + a.y * c.y;     // Sa * conj(Sb)
        double Xi = a.y * c.x - a.x * c.y;
        double mag = sqrt(Xr * Xr + Xi * Xi);
        double w = (k == 0 || k == 2048) ? 1.0 : 2.0;
        double inv = w / (mag + 1e-12);
        phs[k - k0] = make_double2(Xr * inv, Xi * inv);
    }
    __syncthreads();

    if (tid < 41 * NCH) {
        int n = tid % 41;                      // |lag| 0..40
        int c = tid / 41;
        int kk0 = k0 + c * CHLEN;
        int kk1 = kk0 + CHLEN;
        if (kk1 > k1) kk1 = k1;

        double step = (2.0 * PI_D / (double)N_FFT) * (double)n;
        double sv, cv;
        sincos(step, &sv, &cv);
        double wr = cv, wi = sv;               // e^{+i step}
        sincos(step * (double)kk0, &sv, &cv);
        double rr = cv, ri = sv;               // e^{+i step kk0}

        double Cr = 0.0, Ci = 0.0;
        for (int k = kk0; k < kk1; ++k) {
            double2 ph = phs[k - k0];
            Cr = fma(ph.x, rr, Cr);
            Ci = fma(ph.y, ri, Ci);
            double nr = rr * wr - ri * wi;
            double ni = rr * wi + ri * wr;
            rr = nr; ri = ni;
        }
        partCr[tid] = Cr;
        partCi[tid] = Ci;
    }
    __syncthreads();

    if (tid < 41) {
        double Cr = 0.0, Ci = 0.0;
        #pragma unroll
        for (int c = 0; c < NCH; ++c) {
            Cr += partCr[tid + 41 * c];
            Ci += partCi[tid + 41 * c];
        }
        double* outp = cc_part + ((size_t)bp * NSEG + (size_t)seg) * NLAGS;
        outp[MAXTAU + tid] = Cr - Ci;
        if (tid > 0) outp[MAXTAU - tid] = Cr + Ci;
    }
}

// ---------------------------------------------------------------------------
// Kernel 3: grid = (chunk, batch). Stages cc[b] into LDS with the 8-segment
// reduction fused (fixed FP order -> bitwise-identical across blocks ->
// np.argmax tie-break preserved). Per-thread power; wave-shuffle argmax.
// Last block per batch (device-scope ticket) reduces the chunk results and
// writes out[b] directly (finalize fused).
// ---------------------------------------------------------------------------
__global__ __launch_bounds__(256)
void power_argmax_kernel(const double* __restrict__ cc_part,
                         const int* __restrict__ tau,
                         int G, int P,
                         double* __restrict__ pval,
                         int* __restrict__ pidx, int nchunks,
                         int* __restrict__ ticket,
                         const float* __restrict__ grid_x,
                         const float* __restrict__ rec_centroid,
                         float* __restrict__ out) {
    int b     = (int)blockIdx.y;
    int chunk = (int)blockIdx.x;
    int tid   = (int)threadIdx.x;

    __shared__ double ccs[28 * NLAGS];   // 18,144 B
    for (int i = tid; i < 28 * NLAGS; i += 256) {
        int p   = i / NLAGS;
        int lag = i - p * NLAGS;
        const double* src = cc_part + ((size_t)(b * P + p) * NSEG) * NLAGS + lag;
        double v = 0.0;
        #pragma unroll
        for (int s = 0; s < NSEG; ++s) v += src[s * NLAGS];
        ccs[i] = v * (1.0 / (double)N_FFT);
    }
    __syncthreads();

    int g = chunk * 256 + tid;
    double v = -1e300;
    int    gi = 0x7fffffff;
    if (g < G) {
        const int4* tp = (const int4*)(tau + (size_t)g * 28);
        v = 0.0;
        #pragma unroll
        for (int q = 0; q < 7; ++q) {
            int4 tv = tp[q];
            v += ccs[(q * 4 + 0) * NLAGS + tv.x];
            v += ccs[(q * 4 + 1) * NLAGS + tv.y];
            v += ccs[(q * 4 + 2) * NLAGS + tv.z];
            v += ccs[(q * 4 + 3) * NLAGS + tv.w];
        }
        gi = g;
    }

    #pragma unroll
    for (int off = 32; off > 0; off >>= 1) {
        double v2 = __shfl_down(v, off);
        int    i2 = __shfl_down(gi, off);
        if (v2 > v || (v2 == v && i2 < gi)) { v = v2; gi = i2; }
    }
    __shared__ double wval[4];
    __shared__ int    widx[4];
    __shared__ int    lastflag;
    int lane = tid & 63, wv = tid >> 6;
    if (lane == 0) { wval[wv] = v; widx[wv] = gi; }
    __syncthreads();
    if (tid == 0) {
        #pragma unroll
        for (int w = 1; w < 4; ++w) {
            double v2 = wval[w]; int i2 = widx[w];
            if (v2 > v || (v2 == v && i2 < gi)) { v = v2; gi = i2; }
        }
        // device-coherent publish (atomics bypass non-coherent per-XCD L2)
        atomicExch(&pval[b * nchunks + chunk], v);
        atomicExch(&pidx[b * nchunks + chunk], gi);
        __threadfence();
        int old = atomicAdd(&ticket[b], 1);
        lastflag = (old == nchunks - 1) ? 1 : 0;
    }
    __syncthreads();
    if (!lastflag) return;

    // ---- final reduction for this batch (one block, deterministic order) ----
    __threadfence();
    double fv = -1e300; int fgi = 0x7fffffff;
    for (int j = tid; j < nchunks; j += 256) {
        double v2 = atomicAdd(&pval[b * nchunks + j], 0.0);   // atomic read
        int    i2 = atomicAdd(&pidx[b * nchunks + j], 0);
        if (v2 > fv || (v2 == fv && i2 < fgi)) { fv = v2; fgi = i2; }
    }
    #pragma unroll
    for (int off = 32; off > 0; off >>= 1) {
        double v2 = __shfl_down(fv, off);
        int    i2 = __shfl_down(fgi, off);
        if (v2 > fv || (v2 == fv && i2 < fgi)) { fv = v2; fgi = i2; }
    }
    if (lane == 0) { wval[wv] = fv; widx[wv] = fgi; }
    __syncthreads();
    if (tid == 0) {
        #pragma unroll
        for (int w = 1; w < 4; ++w) {
            double v2 = wval[w]; int i2 = widx[w];
            if (v2 > fv || (v2 == fv && i2 < fgi)) { fv = v2; fgi = i2; }
        }
        for (int c = 0; c < 3; ++c)
            out[b * 3 + c] = grid_x[(size_t)fgi * 3 + c] - rec_centroid[c];
    }
}

extern "C" void kernel_launch(void* const* d_in, const int* in_sizes, int n_in,
                              void* d_out, int out_size, void* d_ws, size_t ws_size,
                              hipStream_t stream) {
    const float* signal       = (const float*)d_in[0];
    const float* grid_x       = (const float*)d_in[1];
    const int*   tau          = (const int*)d_in[2];
    const int*   comb         = (const int*)d_in[3];
    const float* rec_centroid = (const float*)d_in[4];
    float* out = (float*)d_out;

    int G  = in_sizes[1] / 3;          // ~31416 grid points
    int P  = in_sizes[3] / 2;          // 28 pairs
    int BM = in_sizes[0] / N_FFT;      // 128 channels
    int B  = BM / 8;                   // 16 batches
    int BP = B * P;                    // 448

    // workspace layout (8B-aligned throughout)
    double*  S       = (double*)d_ws;                          // BM*2049*2
    double*  cc_part = S + (size_t)BM * NBINS * 2;             // BP*8*81
    double2* tw_fft  = (double2*)(cc_part + (size_t)BP * NSEG * NLAGS); // 1024
    double2* tw_post = tw_fft + 1024;                          // 2049
    int nchunks = (G + 255) / 256;
    double*  pval   = (double*)(tw_post + NBINS);
    int*     pidx   = (int*)(pval + (size_t)B * nchunks);
    int*     ticket = pidx + (size_t)B * nchunks;

    table_kernel<<<13, 256, 0, stream>>>(tw_fft, tw_post, ticket, B);
    rfft_kernel<<<BM, 1024, 0, stream>>>(signal, tw_fft, tw_post, S);
    phat_cc_part_kernel<<<BP * NSEG, 256, 0, stream>>>(S, comb, cc_part, P);
    power_argmax_kernel<<<dim3(nchunks, B), 256, 0, stream>>>(
        cc_part, tau, G, P, pval, pidx, nchunks, ticket, grid_x, rec_centroid, out);
}

// Round 6
// 108.319 us; speedup vs baseline: 1.6962x; 1.6962x over previous
//
#include <hip/hip_runtime.h>

#define N_FFT 4096
#define NH    2048          // N_FFT/2 (complex FFT length)
#define NBINS 2049          // N_FFT/2 + 1
#define NLAGS 81            // 2*MAX_TAU + 1
#define MAXTAU 40
#define NSEG  8             // k-segments per (b,p) pair
#define SEGLEN 256
#define PI_D 3.14159265358979323846

// ---------------------------------------------------------------------------
// Kernel 1: rfft per (b,m) channel, fp64, packed-complex radix-2 FFT in LDS.
// Fused: per-block twiddle table (LDS), inline postprocess twiddles, and
// grid-stride zeroing of cc (consumed by phat's atomicAdd).
// ---------------------------------------------------------------------------
__global__ __launch_bounds__(1024)
void rfft_kernel(const float* __restrict__ sig,
                 double* __restrict__ S,
                 double* __restrict__ cc, int ccN) {
    int bm  = (int)blockIdx.x;
    int tid = (int)threadIdx.x;

    __shared__ double2 data[NH];      // 32 KB
    __shared__ double2 tw[NH / 2];    // 16 KB : tw[j] = e^{-2pi i j/2048}

    // zero cc for the atomic accumulation (visible to phat at kernel boundary)
    for (int i = bm * 1024 + tid; i < ccN; i += (int)gridDim.x * 1024)
        cc[i] = 0.0;

    // twiddle table: one entry per thread
    {
        double sv, cv;
        sincos(-(2.0 * PI_D / (double)NH) * (double)tid, &sv, &cv);
        tw[tid] = make_double2(cv, sv);
    }

    // load packed real pairs, scatter to bit-reversed position
    const float2* sp = (const float2*)(sig + (size_t)bm * N_FFT);
    for (int i = tid; i < NH; i += 1024) {
        float2 v = sp[i];
        int j = (int)(__brev((unsigned)i) >> 21);   // 11-bit reverse
        data[j] = make_double2((double)v.x, (double)v.y);
    }
    __syncthreads();

    // 11 radix-2 DIT stages, 1024 butterflies each (1 per thread)
    for (int s = 1; s <= 11; ++s) {
        int half = 1 << (s - 1);
        int g  = tid >> (s - 1);
        int j  = tid & (half - 1);
        int i0 = (g << s) + j;
        int i1 = i0 + half;
        double2 w = tw[j << (11 - s)];
        double2 u = data[i0];
        double2 v = data[i1];
        double vr = v.x * w.x - v.y * w.y;
        double vi = v.x * w.y + v.y * w.x;
        data[i0] = make_double2(u.x + vr, u.y + vi);
        data[i1] = make_double2(u.x - vr, u.y - vi);
        __syncthreads();
    }

    // real-split postprocess -> X[0..2048], twiddle inline
    double* So = S + (size_t)bm * NBINS * 2;
    for (int k = tid; k < NBINS; k += 1024) {
        double2 Zk = data[k & (NH - 1)];
        double2 Zm = data[(NH - k) & (NH - 1)];
        double er = 0.5 * (Zk.x + Zm.x);
        double ei = 0.5 * (Zk.y - Zm.y);
        double dr = Zk.x - Zm.x;
        double di = Zk.y + Zm.y;
        double orr = 0.5 * di;       // O = -i*d/2
        double oii = -0.5 * dr;
        double sv, cv;
        sincos(-(2.0 * PI_D / (double)N_FFT) * (double)k, &sv, &cv);
        So[k * 2]     = er + cv * orr - sv * oii;
        So[k * 2 + 1] = ei + cv * oii + sv * orr;
    }
}

// ---------------------------------------------------------------------------
// Kernel 2: per (b,p,seg): PHAT (irfft weight folded) for 256(+1) bins into
// LDS, then lag partials via n/-n symmetry:
//   Cr(n) = sum_k w*phr*cos(2pi k n/N), Ci(n) = sum_k w*phi*sin(2pi k n/N)
//   cc[40+n] += Cr-Ci ; cc[40-n] += Cr+Ci    (fp64 global atomics)
// Phase 2: 41 |n| values x 6 chunks of 43 bins = 246 threads.
// Atomic order jitter ~1e-16 rel; identical-tau grid points still read
// identical cc entries -> exact ties preserved -> np.argmax tie-break safe.
// ---------------------------------------------------------------------------
#define NCH 6
#define CHLEN 43
__global__ __launch_bounds__(256)
void phat_cc_kernel(const double* __restrict__ S,
                    const int* __restrict__ comb,
                    double* __restrict__ cc, int P) {
    int id  = (int)blockIdx.x;
    int seg = id & (NSEG - 1);
    int bp  = id >> 3;
    int b   = bp / P;
    int p   = bp % P;
    int ma = comb[p * 2 + 0];
    int mb = comb[p * 2 + 1];
    const double2* Sa = (const double2*)(S + ((size_t)(b * 8 + ma)) * NBINS * 2);
    const double2* Sb = (const double2*)(S + ((size_t)(b * 8 + mb)) * NBINS * 2);

    int k0 = seg * SEGLEN;
    int k1 = (seg == NSEG - 1) ? NBINS : (k0 + SEGLEN);   // last seg: 257 bins

    __shared__ double2 phs[SEGLEN + 1];       // 4,112 B
    __shared__ double partCr[41 * NCH];       // 1,968 B
    __shared__ double partCi[41 * NCH];

    int tid = (int)threadIdx.x;
    for (int k = k0 + tid; k < k1; k += 256) {
        double2 a = Sa[k];
        double2 c = Sb[k];
        double Xr = a.x * c.x + a.y * c.y;     // Sa * conj(Sb)
        double Xi = a.y * c.x - a.x * c.y;
        double mag = sqrt(Xr * Xr + Xi * Xi);
        double w = (k == 0 || k == 2048) ? 1.0 : 2.0;
        double inv = w / (mag + 1e-12);
        phs[k - k0] = make_double2(Xr * inv, Xi * inv);
    }
    __syncthreads();

    if (tid < 41 * NCH) {
        int n = tid % 41;                      // |lag| 0..40
        int c = tid / 41;
        int kk0 = k0 + c * CHLEN;
        int kk1 = kk0 + CHLEN;
        if (kk1 > k1) kk1 = k1;

        double step = (2.0 * PI_D / (double)N_FFT) * (double)n;
        double sv, cv;
        sincos(step, &sv, &cv);
        double wr = cv, wi = sv;               // e^{+i step}
        sincos(step * (double)kk0, &sv, &cv);
        double rr = cv, ri = sv;               // e^{+i step kk0}

        double Cr = 0.0, Ci = 0.0;
        for (int k = kk0; k < kk1; ++k) {
            double2 ph = phs[k - k0];
            Cr = fma(ph.x, rr, Cr);
            Ci = fma(ph.y, ri, Ci);
            double nr = rr * wr - ri * wi;
            double ni = rr * wi + ri * wr;
            rr = nr; ri = ni;
        }
        partCr[tid] = Cr;
        partCi[tid] = Ci;
    }
    __syncthreads();

    if (tid < 41) {
        double Cr = 0.0, Ci = 0.0;
        #pragma unroll
        for (int c = 0; c < NCH; ++c) {
            Cr += partCr[tid + 41 * c];
            Ci += partCi[tid + 41 * c];
        }
        double* outp = cc + (size_t)bp * NLAGS;
        atomicAdd(&outp[MAXTAU + tid], Cr - Ci);
        if (tid > 0) atomicAdd(&outp[MAXTAU - tid], Cr + Ci);
    }
}

// ---------------------------------------------------------------------------
// Kernel 3: grid = (chunk, batch). cc[b] staged in LDS (x 1/N); per-thread
// power; wave-shuffle argmax (ties -> lowest index, matching np.argmax).
// ---------------------------------------------------------------------------
__global__ __launch_bounds__(256)
void power_argmax_kernel(const double* __restrict__ cc,
                         const int* __restrict__ tau,
                         int G, int P,
                         double* __restrict__ pval,
                         int* __restrict__ pidx, int nchunks) {
    int b     = (int)blockIdx.y;
    int chunk = (int)blockIdx.x;
    int tid   = (int)threadIdx.x;

    __shared__ double ccs[28 * NLAGS];   // 18,144 B
    const double* csrc = cc + (size_t)b * P * NLAGS;
    for (int i = tid; i < 28 * NLAGS; i += 256)
        ccs[i] = csrc[i] * (1.0 / (double)N_FFT);
    __syncthreads();

    int g = chunk * 256 + tid;
    double v = -1e300;
    int    gi = 0x7fffffff;
    if (g < G) {
        const int4* tp = (const int4*)(tau + (size_t)g * 28);
        v = 0.0;
        #pragma unroll
        for (int q = 0; q < 7; ++q) {
            int4 tv = tp[q];
            v += ccs[(q * 4 + 0) * NLAGS + tv.x];
            v += ccs[(q * 4 + 1) * NLAGS + tv.y];
            v += ccs[(q * 4 + 2) * NLAGS + tv.z];
            v += ccs[(q * 4 + 3) * NLAGS + tv.w];
        }
        gi = g;
    }

    #pragma unroll
    for (int off = 32; off > 0; off >>= 1) {
        double v2 = __shfl_down(v, off);
        int    i2 = __shfl_down(gi, off);
        if (v2 > v || (v2 == v && i2 < gi)) { v = v2; gi = i2; }
    }
    __shared__ double wval[4];
    __shared__ int    widx[4];
    int lane = tid & 63, wv = tid >> 6;
    if (lane == 0) { wval[wv] = v; widx[wv] = gi; }
    __syncthreads();
    if (tid == 0) {
        #pragma unroll
        for (int w = 1; w < 4; ++w) {
            double v2 = wval[w]; int i2 = widx[w];
            if (v2 > v || (v2 == v && i2 < gi)) { v = v2; gi = i2; }
        }
        pval[b * nchunks + chunk] = v;
        pidx[b * nchunks + chunk] = gi;
    }
}

// ---------------------------------------------------------------------------
// Kernel 4: final reduction over chunks (one block per batch, one wave).
// ---------------------------------------------------------------------------
__global__ void finalize_kernel(const double* __restrict__ pval,
                                const int* __restrict__ pidx, int nchunks,
                                const float* __restrict__ grid_x,
                                const float* __restrict__ rec_centroid,
                                float* __restrict__ out) {
    int b = (int)blockIdx.x;
    int l = (int)threadIdx.x;
    double v = -1e300; int gi = 0x7fffffff;
    for (int j = l; j < nchunks; j += 64) {
        double v2 = pval[b * nchunks + j];
        int    i2 = pidx[b * nchunks + j];
        if (v2 > v || (v2 == v && i2 < gi)) { v = v2; gi = i2; }
    }
    #pragma unroll
    for (int off = 32; off > 0; off >>= 1) {
        double v2 = __shfl_down(v, off);
        int    i2 = __shfl_down(gi, off);
        if (v2 > v || (v2 == v && i2 < gi)) { v = v2; gi = i2; }
    }
    if (l == 0) {
        for (int c = 0; c < 3; ++c)
            out[b * 3 + c] = grid_x[(size_t)gi * 3 + c] - rec_centroid[c];
    }
}

extern "C" void kernel_launch(void* const* d_in, const int* in_sizes, int n_in,
                              void* d_out, int out_size, void* d_ws, size_t ws_size,
                              hipStream_t stream) {
    const float* signal       = (const float*)d_in[0];
    const float* grid_x       = (const float*)d_in[1];
    const int*   tau          = (const int*)d_in[2];
    const int*   comb         = (const int*)d_in[3];
    const float* rec_centroid = (const float*)d_in[4];
    float* out = (float*)d_out;

    int G  = in_sizes[1] / 3;          // ~31416 grid points
    int P  = in_sizes[3] / 2;          // 28 pairs
    int BM = in_sizes[0] / N_FFT;      // 128 channels
    int B  = BM / 8;                   // 16 batches
    int BP = B * P;                    // 448

    // workspace layout (8B-aligned throughout)
    double* S  = (double*)d_ws;                    // BM*2049*2 doubles
    double* cc = S + (size_t)BM * NBINS * 2;       // BP*81 doubles
    int nchunks = (G + 255) / 256;
    double* pval = cc + (size_t)BP * NLAGS;
    int*    pidx = (int*)(pval + (size_t)B * nchunks);

    rfft_kernel<<<BM, 1024, 0, stream>>>(signal, S, cc, BP * NLAGS);
    phat_cc_kernel<<<BP * NSEG, 256, 0, stream>>>(S, comb, cc, P);
    power_argmax_kernel<<<dim3(nchunks, B), 256, 0, stream>>>(cc, tau, G, P, pval, pidx, nchunks);
    finalize_kernel<<<B, 64, 0, stream>>>(pval, pidx, nchunks, grid_x, rec_centroid, out);
}

// Round 7
// 97.139 us; speedup vs baseline: 1.8915x; 1.1151x over previous
//
#include <hip/hip_runtime.h>

#define N_FFT 4096
#define NH    2048          // N_FFT/2 (complex FFT length)
#define NBINS 2049          // N_FFT/2 + 1
#define NLAGS 81            // 2*MAX_TAU + 1
#define MAXTAU 40
#define NSEG  8             // k-segments per (b,p) pair
#define SEGLEN 256
#define PI_F 3.14159265358979323846f

// ---------------------------------------------------------------------------
// Kernel 1: rfft per (b,m) channel, fp32, packed-complex radix-2 FFT in LDS.
// Fused: per-block twiddle table (LDS), inline postprocess twiddles, and
// grid-stride zeroing of cc (consumed by phat's atomicAdd).
// fp32 is safe: the problem's own reference is jax float32, so argmax
// decisions are stable at f32 noise level; identical-tau ties stay exact.
// ---------------------------------------------------------------------------
__global__ __launch_bounds__(1024)
void rfft_kernel(const float* __restrict__ sig,
                 float* __restrict__ S,
                 float* __restrict__ cc, int ccN) {
    int bm  = (int)blockIdx.x;
    int tid = (int)threadIdx.x;

    __shared__ float2 data[NH];      // 16 KB
    __shared__ float2 tw[NH / 2];    //  8 KB : tw[j] = e^{-2pi i j/2048}

    // zero cc for the atomic accumulation (visible to phat at kernel boundary)
    for (int i = bm * 1024 + tid; i < ccN; i += (int)gridDim.x * 1024)
        cc[i] = 0.0f;

    // twiddle table: one entry per thread
    {
        float sv, cv;
        sincosf(-(2.0f * PI_F / (float)NH) * (float)tid, &sv, &cv);
        tw[tid] = make_float2(cv, sv);
    }

    // load packed real pairs, scatter to bit-reversed position
    const float2* sp = (const float2*)(sig + (size_t)bm * N_FFT);
    for (int i = tid; i < NH; i += 1024) {
        float2 v = sp[i];
        int j = (int)(__brev((unsigned)i) >> 21);   // 11-bit reverse
        data[j] = v;
    }
    __syncthreads();

    // 11 radix-2 DIT stages, 1024 butterflies each (1 per thread)
    for (int s = 1; s <= 11; ++s) {
        int half = 1 << (s - 1);
        int g  = tid >> (s - 1);
        int j  = tid & (half - 1);
        int i0 = (g << s) + j;
        int i1 = i0 + half;
        float2 w = tw[j << (11 - s)];
        float2 u = data[i0];
        float2 v = data[i1];
        float vr = v.x * w.x - v.y * w.y;
        float vi = v.x * w.y + v.y * w.x;
        data[i0] = make_float2(u.x + vr, u.y + vi);
        data[i1] = make_float2(u.x - vr, u.y - vi);
        __syncthreads();
    }

    // real-split postprocess -> X[0..2048], twiddle inline
    float* So = S + (size_t)bm * NBINS * 2;
    for (int k = tid; k < NBINS; k += 1024) {
        float2 Zk = data[k & (NH - 1)];
        float2 Zm = data[(NH - k) & (NH - 1)];
        float er = 0.5f * (Zk.x + Zm.x);
        float ei = 0.5f * (Zk.y - Zm.y);
        float dr = Zk.x - Zm.x;
        float di = Zk.y + Zm.y;
        float orr = 0.5f * di;       // O = -i*d/2
        float oii = -0.5f * dr;
        float sv, cv;
        sincosf(-(2.0f * PI_F / (float)N_FFT) * (float)k, &sv, &cv);
        So[k * 2]     = er + cv * orr - sv * oii;
        So[k * 2 + 1] = ei + cv * oii + sv * orr;
    }
}

// ---------------------------------------------------------------------------
// Kernel 2: per (b,p,seg): PHAT (irfft weight folded) for 256(+1) bins into
// LDS, then lag partials via n/-n symmetry:
//   Cr(n) = sum_k w*phr*cos(2pi k n/N), Ci(n) = sum_k w*phi*sin(2pi k n/N)
//   cc[40+n] += Cr-Ci ; cc[40-n] += Cr+Ci    (fp32 global atomics)
// Phase 2: 41 |n| values x 6 chunks of 43 bins = 246 threads.
// ---------------------------------------------------------------------------
#define NCH 6
#define CHLEN 43
__global__ __launch_bounds__(256)
void phat_cc_kernel(const float* __restrict__ S,
                    const int* __restrict__ comb,
                    float* __restrict__ cc, int P) {
    int id  = (int)blockIdx.x;
    int seg = id & (NSEG - 1);
    int bp  = id >> 3;
    int b   = bp / P;
    int p   = bp % P;
    int ma = comb[p * 2 + 0];
    int mb = comb[p * 2 + 1];
    const float2* Sa = (const float2*)(S + ((size_t)(b * 8 + ma)) * NBINS * 2);
    const float2* Sb = (const float2*)(S + ((size_t)(b * 8 + mb)) * NBINS * 2);

    int k0 = seg * SEGLEN;
    int k1 = (seg == NSEG - 1) ? NBINS : (k0 + SEGLEN);   // last seg: 257 bins

    __shared__ float2 phs[SEGLEN + 1];       // 2,056 B
    __shared__ float partCr[41 * NCH];       //   984 B
    __shared__ float partCi[41 * NCH];

    int tid = (int)threadIdx.x;
    for (int k = k0 + tid; k < k1; k += 256) {
        float2 a = Sa[k];
        float2 c = Sb[k];
        float Xr = a.x * c.x + a.y * c.y;     // Sa * conj(Sb)
        float Xi = a.y * c.x - a.x * c.y;
        float mag = sqrtf(Xr * Xr + Xi * Xi);
        float w = (k == 0 || k == 2048) ? 1.0f : 2.0f;
        float inv = w / (mag + 1e-12f);
        phs[k - k0] = make_float2(Xr * inv, Xi * inv);
    }
    __syncthreads();

    if (tid < 41 * NCH) {
        int n = tid % 41;                      // |lag| 0..40
        int c = tid / 41;
        int kk0 = k0 + c * CHLEN;
        int kk1 = kk0 + CHLEN;
        if (kk1 > k1) kk1 = k1;

        float step = (2.0f * PI_F / (float)N_FFT) * (float)n;
        float sv, cv;
        sincosf(step, &sv, &cv);
        float wr = cv, wi = sv;               // e^{+i step}
        sincosf(step * (float)kk0, &sv, &cv);
        float rr = cv, ri = sv;               // e^{+i step kk0}

        float Cr = 0.0f, Ci = 0.0f;
        for (int k = kk0; k < kk1; ++k) {
            float2 ph = phs[k - k0];
            Cr = fmaf(ph.x, rr, Cr);
            Ci = fmaf(ph.y, ri, Ci);
            float nr = rr * wr - ri * wi;
            float ni = rr * wi + ri * wr;
            rr = nr; ri = ni;
        }
        partCr[tid] = Cr;
        partCi[tid] = Ci;
    }
    __syncthreads();

    if (tid < 41) {
        float Cr = 0.0f, Ci = 0.0f;
        #pragma unroll
        for (int c = 0; c < NCH; ++c) {
            Cr += partCr[tid + 41 * c];
            Ci += partCi[tid + 41 * c];
        }
        float* outp = cc + (size_t)bp * NLAGS;
        atomicAdd(&outp[MAXTAU + tid], Cr - Ci);
        if (tid > 0) atomicAdd(&outp[MAXTAU - tid], Cr + Ci);
    }
}

// ---------------------------------------------------------------------------
// Kernel 3: grid = (chunk, batch). cc[b] staged in LDS (x 1/N); per-thread
// power; wave-shuffle argmax (ties -> lowest index, matching np.argmax).
// ---------------------------------------------------------------------------
__global__ __launch_bounds__(256)
void power_argmax_kernel(const float* __restrict__ cc,
                         const int* __restrict__ tau,
                         int G, int P,
                         float* __restrict__ pval,
                         int* __restrict__ pidx, int nchunks) {
    int b     = (int)blockIdx.y;
    int chunk = (int)blockIdx.x;
    int tid   = (int)threadIdx.x;

    __shared__ float ccs[28 * NLAGS];   // 9,072 B
    const float* csrc = cc + (size_t)b * P * NLAGS;
    for (int i = tid; i < 28 * NLAGS; i += 256)
        ccs[i] = csrc[i] * (1.0f / (float)N_FFT);
    __syncthreads();

    int g = chunk * 256 + tid;
    float v = -1e30f;
    int   gi = 0x7fffffff;
    if (g < G) {
        const int4* tp = (const int4*)(tau + (size_t)g * 28);
        v = 0.0f;
        #pragma unroll
        for (int q = 0; q < 7; ++q) {
            int4 tv = tp[q];
            v += ccs[(q * 4 + 0) * NLAGS + tv.x];
            v += ccs[(q * 4 + 1) * NLAGS + tv.y];
            v += ccs[(q * 4 + 2) * NLAGS + tv.z];
            v += ccs[(q * 4 + 3) * NLAGS + tv.w];
        }
        gi = g;
    }

    #pragma unroll
    for (int off = 32; off > 0; off >>= 1) {
        float v2 = __shfl_down(v, off);
        int   i2 = __shfl_down(gi, off);
        if (v2 > v || (v2 == v && i2 < gi)) { v = v2; gi = i2; }
    }
    __shared__ float wval[4];
    __shared__ int   widx[4];
    int lane = tid & 63, wv = tid >> 6;
    if (lane == 0) { wval[wv] = v; widx[wv] = gi; }
    __syncthreads();
    if (tid == 0) {
        #pragma unroll
        for (int w = 1; w < 4; ++w) {
            float v2 = wval[w]; int i2 = widx[w];
            if (v2 > v || (v2 == v && i2 < gi)) { v = v2; gi = i2; }
        }
        pval[b * nchunks + chunk] = v;
        pidx[b * nchunks + chunk] = gi;
    }
}

// ---------------------------------------------------------------------------
// Kernel 4: final reduction over chunks (one block per batch, one wave).
// ---------------------------------------------------------------------------
__global__ void finalize_kernel(const float* __restrict__ pval,
                                const int* __restrict__ pidx, int nchunks,
                                const float* __restrict__ grid_x,
                                const float* __restrict__ rec_centroid,
                                float* __restrict__ out) {
    int b = (int)blockIdx.x;
    int l = (int)threadIdx.x;
    float v = -1e30f; int gi = 0x7fffffff;
    for (int j = l; j < nchunks; j += 64) {
        float v2 = pval[b * nchunks + j];
        int   i2 = pidx[b * nchunks + j];
        if (v2 > v || (v2 == v && i2 < gi)) { v = v2; gi = i2; }
    }
    #pragma unroll
    for (int off = 32; off > 0; off >>= 1) {
        float v2 = __shfl_down(v, off);
        int   i2 = __shfl_down(gi, off);
        if (v2 > v || (v2 == v && i2 < gi)) { v = v2; gi = i2; }
    }
    if (l == 0) {
        for (int c = 0; c < 3; ++c)
            out[b * 3 + c] = grid_x[(size_t)gi * 3 + c] - rec_centroid[c];
    }
}

extern "C" void kernel_launch(void* const* d_in, const int* in_sizes, int n_in,
                              void* d_out, int out_size, void* d_ws, size_t ws_size,
                              hipStream_t stream) {
    const float* signal       = (const float*)d_in[0];
    const float* grid_x       = (const float*)d_in[1];
    const int*   tau          = (const int*)d_in[2];
    const int*   comb         = (const int*)d_in[3];
    const float* rec_centroid = (const float*)d_in[4];
    float* out = (float*)d_out;

    int G  = in_sizes[1] / 3;          // ~31416 grid points
    int P  = in_sizes[3] / 2;          // 28 pairs
    int BM = in_sizes[0] / N_FFT;      // 128 channels
    int B  = BM / 8;                   // 16 batches
    int BP = B * P;                    // 448

    // workspace layout (4B-aligned throughout)
    float* S  = (float*)d_ws;                      // BM*2049*2 floats (2.1 MB)
    float* cc = S + (size_t)BM * NBINS * 2;        // BP*81 floats
    int nchunks = (G + 255) / 256;
    float* pval = cc + (size_t)BP * NLAGS;
    int*   pidx = (int*)(pval + (size_t)B * nchunks);

    rfft_kernel<<<BM, 1024, 0, stream>>>(signal, S, cc, BP * NLAGS);
    phat_cc_kernel<<<BP * NSEG, 256, 0, stream>>>(S, comb, cc, P);
    power_argmax_kernel<<<dim3(nchunks, B), 256, 0, stream>>>(cc, tau, G, P, pval, pidx, nchunks);
    finalize_kernel<<<B, 64, 0, stream>>>(pval, pidx, nchunks, grid_x, rec_centroid, out);
}